// Round 10
// baseline (96.241 us; speedup 1.0000x reference)
//
#include <hip/hip_runtime.h>
#include <cmath>

#define NF 4096
#define PI2F 6.2831853071795864769f

typedef float2 cf;

__device__ __forceinline__ cf cmulf(cf a, cf b){
  return make_float2(fmaf(a.x, b.x, -(a.y*b.y)), fmaf(a.x, b.y, a.y*b.x));
}
__device__ __forceinline__ cf cadd(cf a, cf b){ return make_float2(a.x+b.x, a.y+b.y); }
__device__ __forceinline__ cf csub(cf a, cf b){ return make_float2(a.x-b.x, a.y-b.y); }

// ---- k_main LDS map: additive pad (PROVEN 52us config, rounds 5+6+8+9) ----
__device__ __forceinline__ int phys8(int i){ return i + (i >> 3); }

// base-8 digit reversal of a 12-bit index (involution): slot w <-> true freq k
__device__ __forceinline__ int rev8(int i){
  return ((i & 7) << 9) | (((i >> 3) & 7) << 6) | (((i >> 6) & 7) << 3) | ((i >> 9) & 7);
}

// radix-8 DFT in registers; INV=0 forward (e^{-i}), INV=1 inverse (e^{+i}), unnormalized.
template<int INV>
__device__ __forceinline__ void dft8(cf* v){
  const float HF = 0.7071067811865476f;
  cf e0,e1,e2,e3,o0,o1,o2,o3;
  {
    cf t0 = cadd(v[0], v[4]);
    cf t1 = csub(v[0], v[4]);
    cf t2 = cadd(v[2], v[6]);
    cf t3 = csub(v[2], v[6]);
    e0 = cadd(t0,t2); e2 = csub(t0,t2);
    if (!INV){ e1 = make_float2(t1.x+t3.y, t1.y-t3.x); e3 = make_float2(t1.x-t3.y, t1.y+t3.x); }
    else     { e1 = make_float2(t1.x-t3.y, t1.y+t3.x); e3 = make_float2(t1.x+t3.y, t1.y-t3.x); }
  }
  {
    cf t0 = cadd(v[1], v[5]);
    cf t1 = csub(v[1], v[5]);
    cf t2 = cadd(v[3], v[7]);
    cf t3 = csub(v[3], v[7]);
    o0 = cadd(t0,t2); o2 = csub(t0,t2);
    if (!INV){ o1 = make_float2(t1.x+t3.y, t1.y-t3.x); o3 = make_float2(t1.x-t3.y, t1.y+t3.x); }
    else     { o1 = make_float2(t1.x-t3.y, t1.y+t3.x); o3 = make_float2(t1.x+t3.y, t1.y-t3.x); }
  }
  cf w1, w2, w3;
  if (!INV){
    w1 = make_float2(HF*(o1.x + o1.y), HF*(o1.y - o1.x));
    w2 = make_float2(o2.y, -o2.x);
    w3 = make_float2(HF*(o3.y - o3.x), -HF*(o3.x + o3.y));
  } else {
    w1 = make_float2(HF*(o1.x - o1.y), HF*(o1.y + o1.x));
    w2 = make_float2(-o2.y, o2.x);
    w3 = make_float2(-HF*(o3.x + o3.y), HF*(o3.x - o3.y));
  }
  v[0] = cadd(e0,o0); v[4] = csub(e0,o0);
  v[1] = cadd(e1,w1); v[5] = csub(e1,w1);
  v[2] = cadd(e2,w2); v[6] = csub(e2,w2);
  v[3] = cadd(e3,w3); v[7] = csub(e3,w3);
}

// v[r] *= e^{i*ang*r}, r=1..7. Chebyshev power build: T_{r+1} = 2c*T_r - T_{r-1}
__device__ __forceinline__ void twiddle8(cf* v, float ang){
  float s, c;
  __sincosf(ang, &s, &c);
  float c2 = 2.0f * c;
  cf T[8];
  T[1] = make_float2(c, s);
  T[2] = make_float2(fmaf(c2, c, -1.0f), c2 * s);
#pragma unroll
  for (int r = 3; r < 8; ++r)
    T[r] = make_float2(fmaf(c2, T[r-1].x, -T[r-2].x), fmaf(c2, T[r-1].y, -T[r-2].y));
#pragma unroll
  for (int r = 1; r < 8; ++r) v[r] = cmulf(v[r], T[r]);
}

__device__ __forceinline__ float fast_tanh(float x){
  float e = __expf(2.0f*x);
  return 1.0f - __fdividef(2.0f, e + 1.0f);
}

// ---------------- k_geo: closed-form spectral tables ------------------------------
// One block per p. Thread 0 computes per-p constants in f64 (atan2/log2/exp2/
// sincospi once, not 4096x); per-element work is pure f32 (2 sincospif + 1 div).
// Precision: |denom|>=~1e-3, f32 sincos err ~1e-7 -> rel err ~1e-4 in G,
// abs err ~1e-5 in M -- far below the 2e-2 threshold.
// For slot w (k_main's base-8 digitrev order), true freq k = rev8(w):
//   G1 = (1-lam^N)/(1-lam*cis(-2pi k/N)),  G2 = same at +k
//   A  = (G1 + conj(G2))/2/N   (multiplies Re(W));  B2 = i*(G1 - conj(G2))/2/N (Im(W))
// tab[p][w] = (A.r, A.i, B2.r, B2.i)
__global__ __launch_bounds__(1024) void k_geo(const float* __restrict__ Lam,
                                              float4* __restrict__ tab){
  __shared__ float sh[4];
  const int p = blockIdx.x;
  const int t = threadIdx.x;
  if (t == 0){
    double lr = (double)Lam[2*p], li = (double)Lam[2*p+1];
    double r2 = lr*lr + li*li;
    double tt = atan2(li, lr) * 0.15915494309189535;   // phase in turns
    double rN = exp2(4096.0 * (0.5 * log2(r2)));       // |lambda|^N
    double pN = 4096.0 * tt;  pN -= floor(pN);
    double sN, cN;  sincospi(2.0*pN, &sN, &cN);
    sh[0] = (float)tt;
    sh[1] = (float)sqrt(r2);
    sh[2] = (float)(1.0 - rN*cN);                      // num.re
    sh[3] = (float)(-rN*sN);                           // num.im
  }
  __syncthreads();
  const float tt = sh[0], r = sh[1], numr = sh[2], numi = sh[3];
  const float hN = 0.5f/4096.0f;
  float4* dst = tab + (size_t)p*4096;
#pragma unroll
  for (int s = 0; s < 4; ++s){
    int w = s*1024 + t;                 // coalesced float4 stores
    int k = rev8(w);
    float kf = (float)k * (1.0f/4096.0f);
    float s1, c1;  sincospif(2.0f*(tt - kf), &s1, &c1);
    float d1r = fmaf(-r, c1, 1.0f), d1i = -r*s1;
    float i1 = 1.0f / fmaf(d1r, d1r, d1i*d1i);
    float g1r = (numr*d1r + numi*d1i)*i1;
    float g1i = (numi*d1r - numr*d1i)*i1;
    float s2, c2;  sincospif(2.0f*(tt + kf), &s2, &c2);
    float d2r = fmaf(-r, c2, 1.0f), d2i = -r*s2;
    float i2 = 1.0f / fmaf(d2r, d2r, d2i*d2i);
    float g2r = (numr*d2r + numi*d2i)*i2;
    float g2i = (numi*d2r - numr*d2i)*i2;
    dst[w] = make_float4( (g1r + g2r)*hN, (g1i - g2i)*hN,
                         -(g1i + g2i)*hN, (g1r - g2r)*hN);
  }
}

// ---------------- k_red: M[h][w] = sum_p Wr*A + Wi*B2  (+ dd/N on real) ------------
// block: 512 thr = 8 waves x 4 h each -> h-group 32; k-slice 128; grid 8x32 = 256.
__global__ __launch_bounds__(512,4) void k_red(
    const float* __restrict__ C, const float* __restrict__ Bb,
    const float4* __restrict__ tab, const float* __restrict__ D,
    cf* __restrict__ M){
  __shared__ cf Wsh[32][64];          // 16 KiB
  __shared__ float4 Tt[8][128];       // 16 KiB
  const int t  = threadIdx.x;
  const int hg = blockIdx.x >> 5;     // 0..7
  const int ls = blockIdx.x & 31;     // 0..31
  const int h0 = hg*32;
  const int w0 = ls*128;
#pragma unroll
  for (int e = 0; e < 4; ++e){
    int idx = e*512 + t;
    int hl = idx >> 6, p = idx & 63;
    int h = h0 + hl;
    cf cc = ((const cf*)C)[h*64 + p];
    cf bb = ((const cf*)Bb)[p*256 + h];
    Wsh[hl][p] = cmulf(cc, bb);
  }
  const int wave = t >> 6;
  const int lane = t & 63;
  const int hh = wave*4;              // this wave's 4 local h
  float accr[2][4] = {{0,0,0,0},{0,0,0,0}};
  float acci[2][4] = {{0,0,0,0},{0,0,0,0}};
  for (int pc = 0; pc < 8; ++pc){
    __syncthreads();
#pragma unroll
    for (int e = 0; e < 2; ++e){
      int idx = e*512 + t;            // 1024 float4 tile entries
      int row = idx >> 7, col = idx & 127;
      Tt[row][col] = tab[(size_t)(pc*8 + row)*4096 + w0 + col];
    }
    __syncthreads();
#pragma unroll
    for (int p = 0; p < 8; ++p){
      cf Wc[4];
#pragma unroll
      for (int h = 0; h < 4; ++h) Wc[h] = Wsh[hh + h][pc*8 + p];   // broadcast
#pragma unroll
      for (int j = 0; j < 2; ++j){
        float4 f = Tt[p][lane + 64*j];
#pragma unroll
        for (int h = 0; h < 4; ++h){
          accr[j][h] = fmaf(Wc[h].x, f.x, fmaf(Wc[h].y, f.z, accr[j][h]));
          acci[j][h] = fmaf(Wc[h].x, f.y, fmaf(Wc[h].y, f.w, acci[j][h]));
        }
      }
    }
  }
  const float invN = 1.0f/4096.0f;
#pragma unroll
  for (int h = 0; h < 4; ++h){
    int hq = h0 + hh + h;
    float dd = D[hq*256 + hq] * invN;
#pragma unroll
    for (int j = 0; j < 2; ++j)
      M[(size_t)hq*NF + w0 + lane + 64*j] = make_float2(accr[j][h] + dd, acci[j][h]);
  }
}

// ------------- main: z = u0 + i u1 ; FFT ; *M ; IFFT ; tanh ; store ------------------
// PROVEN round-5/6/8/9 config (phys8, 36 KiB). Only change: all 4 M float4 loads
// issued at kernel ENTRY so the L3-hit latency hides under stage-1 compute
// (they drain at the stage-1 barrier, ~700cy after issue). VGPR 32->~48 <= 64 cap.
__global__ __launch_bounds__(512,8) void k_main(
    const float* __restrict__ u, const cf* __restrict__ M, float* __restrict__ out){
  __shared__ cf X[4608];                 // 36 KiB
  const int t  = threadIdx.x;
  const int h  = blockIdx.x >> 3;
  const int pr = blockIdx.x & 7;
  const size_t row0 = ((size_t)pr*256 + h)*(size_t)NF;
  const size_t row1 = row0 + (size_t)8*256*NF;
  const float* u0 = u + row0;
  const float* u1 = u + row1;
  cf v[8];
  // u loads (consumed immediately) ...
#pragma unroll
  for (int q = 0; q < 8; ++q) v[q] = make_float2(u0[t + 512*q], u1[t + 512*q]);
  // ... then M loads (consumed after fwd stage 4): in flight across stage 1
  const float4* Mr = (const float4*)(M + (size_t)h*NF + 8*t);
  float4 mf0 = Mr[0], mf1 = Mr[1], mf2 = Mr[2], mf3 = Mr[3];
  // fwd stage 1 (span 4096)
  dft8<0>(v);
  twiddle8(v, -(PI2F/4096.0f)*(float)t);
#pragma unroll
  for (int r = 0; r < 8; ++r) X[phys8(t + 512*r)] = v[r];
  __syncthreads();
  // fwd stage 2 (span 512)
  const int b2 = ((t >> 6) << 9) | (t & 63);
#pragma unroll
  for (int q = 0; q < 8; ++q) v[q] = X[phys8(b2 + 64*q)];
  dft8<0>(v);
  twiddle8(v, -(PI2F/512.0f)*(float)(t & 63));
#pragma unroll
  for (int r = 0; r < 8; ++r) X[phys8(b2 + 64*r)] = v[r];
  __syncthreads();
  // fwd stage 3 (span 64)
  const int b3 = ((t >> 3) << 6) | (t & 7);
#pragma unroll
  for (int q = 0; q < 8; ++q) v[q] = X[phys8(b3 + 8*q)];
  dft8<0>(v);
  twiddle8(v, -(PI2F/64.0f)*(float)(t & 7));
#pragma unroll
  for (int r = 0; r < 8; ++r) X[phys8(b3 + 8*r)] = v[r];
  __syncthreads();
  // fwd stage 4 (span 8, contiguous) + pointwise + inv stage 1, in registers
#pragma unroll
  for (int q = 0; q < 8; ++q) v[q] = X[phys8(8*t + q)];
  dft8<0>(v);
  v[0] = cmulf(v[0], make_float2(mf0.x, mf0.y));
  v[1] = cmulf(v[1], make_float2(mf0.z, mf0.w));
  v[2] = cmulf(v[2], make_float2(mf1.x, mf1.y));
  v[3] = cmulf(v[3], make_float2(mf1.z, mf1.w));
  v[4] = cmulf(v[4], make_float2(mf2.x, mf2.y));
  v[5] = cmulf(v[5], make_float2(mf2.z, mf2.w));
  v[6] = cmulf(v[6], make_float2(mf3.x, mf3.y));
  v[7] = cmulf(v[7], make_float2(mf3.z, mf3.w));
  dft8<1>(v);
#pragma unroll
  for (int q = 0; q < 8; ++q) X[phys8(8*t + q)] = v[q];
  __syncthreads();
  // inv stage 3
#pragma unroll
  for (int r = 0; r < 8; ++r) v[r] = X[phys8(b3 + 8*r)];
  twiddle8(v, (PI2F/64.0f)*(float)(t & 7));
  dft8<1>(v);
#pragma unroll
  for (int q = 0; q < 8; ++q) X[phys8(b3 + 8*q)] = v[q];
  __syncthreads();
  // inv stage 2
#pragma unroll
  for (int r = 0; r < 8; ++r) v[r] = X[phys8(b2 + 64*r)];
  twiddle8(v, (PI2F/512.0f)*(float)(t & 63));
  dft8<1>(v);
#pragma unroll
  for (int q = 0; q < 8; ++q) X[phys8(b2 + 64*q)] = v[q];
  __syncthreads();
  // inv stage 1 + epilogue
#pragma unroll
  for (int r = 0; r < 8; ++r) v[r] = X[phys8(t + 512*r)];
  twiddle8(v, (PI2F/4096.0f)*(float)t);
  dft8<1>(v);
  float* o0 = out + row0;
  float* o1 = out + row1;
#pragma unroll
  for (int q = 0; q < 8; ++q){
    o0[t + 512*q] = fast_tanh(v[q].x);
    o1[t + 512*q] = fast_tanh(v[q].y);
  }
}

extern "C" void kernel_launch(void* const* d_in, const int* in_sizes, int n_in,
                              void* d_out, int out_size, void* d_ws, size_t ws_size,
                              hipStream_t stream){
  const float* u   = (const float*)d_in[0];
  const float* C   = (const float*)d_in[1];
  const float* D   = (const float*)d_in[2];
  const float* Bb  = (const float*)d_in[3];
  const float* Lam = (const float*)d_in[4];
  float* out = (float*)d_out;
  char* ws = (char*)d_ws;
  cf*     M   = (cf*)ws;                              // 8 MiB: [256][4096] cf, rev8 slot order
  float4* tab = (float4*)(ws + (size_t)(8u << 20));   // 4 MiB: [64][4096] float4 (A, iB)

  k_geo <<<dim3(64),   dim3(1024), 0, stream>>>(Lam, tab);
  k_red <<<dim3(256),  dim3(512),  0, stream>>>(C, Bb, tab, D, M);
  k_main<<<dim3(2048), dim3(512),  0, stream>>>(u, M, out);
}

// Round 11
// 65.139 us; speedup vs baseline: 1.4775x; 1.4775x over previous
//
#include <hip/hip_runtime.h>
#include <cmath>

#define NF 4096
#define PI2F 6.2831853071795864769f

typedef float2 cf;

__device__ __forceinline__ cf cmulf(cf a, cf b){
  return make_float2(fmaf(a.x, b.x, -(a.y*b.y)), fmaf(a.x, b.y, a.y*b.x));
}
__device__ __forceinline__ cf cadd(cf a, cf b){ return make_float2(a.x+b.x, a.y+b.y); }
__device__ __forceinline__ cf csub(cf a, cf b){ return make_float2(a.x-b.x, a.y-b.y); }

// ---- k_main LDS map: additive pad (PROVEN 52us config, rounds 5+6+8+9) ----
__device__ __forceinline__ int phys8(int i){ return i + (i >> 3); }

// base-8 digit reversal of a 12-bit index (involution): slot w <-> true freq k
__device__ __forceinline__ int rev8(int i){
  return ((i & 7) << 9) | (((i >> 3) & 7) << 6) | (((i >> 6) & 7) << 3) | ((i >> 9) & 7);
}

// radix-8 DFT in registers; INV=0 forward (e^{-i}), INV=1 inverse (e^{+i}), unnormalized.
template<int INV>
__device__ __forceinline__ void dft8(cf* v){
  const float HF = 0.7071067811865476f;
  cf e0,e1,e2,e3,o0,o1,o2,o3;
  {
    cf t0 = cadd(v[0], v[4]);
    cf t1 = csub(v[0], v[4]);
    cf t2 = cadd(v[2], v[6]);
    cf t3 = csub(v[2], v[6]);
    e0 = cadd(t0,t2); e2 = csub(t0,t2);
    if (!INV){ e1 = make_float2(t1.x+t3.y, t1.y-t3.x); e3 = make_float2(t1.x-t3.y, t1.y+t3.x); }
    else     { e1 = make_float2(t1.x-t3.y, t1.y+t3.x); e3 = make_float2(t1.x+t3.y, t1.y-t3.x); }
  }
  {
    cf t0 = cadd(v[1], v[5]);
    cf t1 = csub(v[1], v[5]);
    cf t2 = cadd(v[3], v[7]);
    cf t3 = csub(v[3], v[7]);
    o0 = cadd(t0,t2); o2 = csub(t0,t2);
    if (!INV){ o1 = make_float2(t1.x+t3.y, t1.y-t3.x); o3 = make_float2(t1.x-t3.y, t1.y+t3.x); }
    else     { o1 = make_float2(t1.x-t3.y, t1.y+t3.x); o3 = make_float2(t1.x+t3.y, t1.y-t3.x); }
  }
  cf w1, w2, w3;
  if (!INV){
    w1 = make_float2(HF*(o1.x + o1.y), HF*(o1.y - o1.x));
    w2 = make_float2(o2.y, -o2.x);
    w3 = make_float2(HF*(o3.y - o3.x), -HF*(o3.x + o3.y));
  } else {
    w1 = make_float2(HF*(o1.x - o1.y), HF*(o1.y + o1.x));
    w2 = make_float2(-o2.y, o2.x);
    w3 = make_float2(-HF*(o3.x + o3.y), HF*(o3.x - o3.y));
  }
  v[0] = cadd(e0,o0); v[4] = csub(e0,o0);
  v[1] = cadd(e1,w1); v[5] = csub(e1,w1);
  v[2] = cadd(e2,w2); v[6] = csub(e2,w2);
  v[3] = cadd(e3,w3); v[7] = csub(e3,w3);
}

// v[r] *= e^{i*ang*r}, r=1..7. Chebyshev power build: T_{r+1} = 2c*T_r - T_{r-1}
__device__ __forceinline__ void twiddle8(cf* v, float ang){
  float s, c;
  __sincosf(ang, &s, &c);
  float c2 = 2.0f * c;
  cf T[8];
  T[1] = make_float2(c, s);
  T[2] = make_float2(fmaf(c2, c, -1.0f), c2 * s);
#pragma unroll
  for (int r = 3; r < 8; ++r)
    T[r] = make_float2(fmaf(c2, T[r-1].x, -T[r-2].x), fmaf(c2, T[r-1].y, -T[r-2].y));
#pragma unroll
  for (int r = 1; r < 8; ++r) v[r] = cmulf(v[r], T[r]);
}

__device__ __forceinline__ float fast_tanh(float x){
  float e = __expf(2.0f*x);
  return 1.0f - __fdividef(2.0f, e + 1.0f);
}

// ---------------- k_geo: closed-form spectral tables ------------------------------
// One block per p; thread 0 computes per-p constants in f64 once; per-element
// work is pure f32 (2 sincospif + 1 rcp). Abs err in M ~1e-5 << 2e-2 threshold.
__global__ __launch_bounds__(1024) void k_geo(const float* __restrict__ Lam,
                                              float4* __restrict__ tab){
  __shared__ float sh[4];
  const int p = blockIdx.x;
  const int t = threadIdx.x;
  if (t == 0){
    double lr = (double)Lam[2*p], li = (double)Lam[2*p+1];
    double r2 = lr*lr + li*li;
    double tt = atan2(li, lr) * 0.15915494309189535;   // phase in turns
    double rN = exp2(4096.0 * (0.5 * log2(r2)));       // |lambda|^N
    double pN = 4096.0 * tt;  pN -= floor(pN);
    double sN, cN;  sincospi(2.0*pN, &sN, &cN);
    sh[0] = (float)tt;
    sh[1] = (float)sqrt(r2);
    sh[2] = (float)(1.0 - rN*cN);                      // num.re
    sh[3] = (float)(-rN*sN);                           // num.im
  }
  __syncthreads();
  const float tt = sh[0], r = sh[1], numr = sh[2], numi = sh[3];
  const float hN = 0.5f/4096.0f;
  float4* dst = tab + (size_t)p*4096;
#pragma unroll
  for (int s = 0; s < 4; ++s){
    int w = s*1024 + t;                 // coalesced float4 stores
    int k = rev8(w);
    float kf = (float)k * (1.0f/4096.0f);
    float s1, c1;  sincospif(2.0f*(tt - kf), &s1, &c1);
    float d1r = fmaf(-r, c1, 1.0f), d1i = -r*s1;
    float i1 = 1.0f / fmaf(d1r, d1r, d1i*d1i);
    float g1r = (numr*d1r + numi*d1i)*i1;
    float g1i = (numi*d1r - numr*d1i)*i1;
    float s2, c2;  sincospif(2.0f*(tt + kf), &s2, &c2);
    float d2r = fmaf(-r, c2, 1.0f), d2i = -r*s2;
    float i2 = 1.0f / fmaf(d2r, d2r, d2i*d2i);
    float g2r = (numr*d2r + numi*d2i)*i2;
    float g2i = (numi*d2r - numr*d2i)*i2;
    dst[w] = make_float4( (g1r + g2r)*hN, (g1i - g2i)*hN,
                         -(g1i + g2i)*hN, (g1r - g2r)*hN);
  }
}

// ---------------- k_red: M[h][w] = sum_p Wr*A + Wi*B2  (+ dd/N on real) ------------
// block: 512 thr = 8 waves x 4 h each -> h-group 32; k-slice 128; grid 8x32 = 256.
__global__ __launch_bounds__(512,4) void k_red(
    const float* __restrict__ C, const float* __restrict__ Bb,
    const float4* __restrict__ tab, const float* __restrict__ D,
    cf* __restrict__ M){
  __shared__ cf Wsh[32][64];          // 16 KiB
  __shared__ float4 Tt[8][128];       // 16 KiB
  const int t  = threadIdx.x;
  const int hg = blockIdx.x >> 5;     // 0..7
  const int ls = blockIdx.x & 31;     // 0..31
  const int h0 = hg*32;
  const int w0 = ls*128;
#pragma unroll
  for (int e = 0; e < 4; ++e){
    int idx = e*512 + t;
    int hl = idx >> 6, p = idx & 63;
    int h = h0 + hl;
    cf cc = ((const cf*)C)[h*64 + p];
    cf bb = ((const cf*)Bb)[p*256 + h];
    Wsh[hl][p] = cmulf(cc, bb);
  }
  const int wave = t >> 6;
  const int lane = t & 63;
  const int hh = wave*4;              // this wave's 4 local h
  float accr[2][4] = {{0,0,0,0},{0,0,0,0}};
  float acci[2][4] = {{0,0,0,0},{0,0,0,0}};
  for (int pc = 0; pc < 8; ++pc){
    __syncthreads();
#pragma unroll
    for (int e = 0; e < 2; ++e){
      int idx = e*512 + t;            // 1024 float4 tile entries
      int row = idx >> 7, col = idx & 127;
      Tt[row][col] = tab[(size_t)(pc*8 + row)*4096 + w0 + col];
    }
    __syncthreads();
#pragma unroll
    for (int p = 0; p < 8; ++p){
      cf Wc[4];
#pragma unroll
      for (int h = 0; h < 4; ++h) Wc[h] = Wsh[hh + h][pc*8 + p];   // broadcast
#pragma unroll
      for (int j = 0; j < 2; ++j){
        float4 f = Tt[p][lane + 64*j];
#pragma unroll
        for (int h = 0; h < 4; ++h){
          accr[j][h] = fmaf(Wc[h].x, f.x, fmaf(Wc[h].y, f.z, accr[j][h]));
          acci[j][h] = fmaf(Wc[h].x, f.y, fmaf(Wc[h].y, f.w, acci[j][h]));
        }
      }
    }
  }
  const float invN = 1.0f/4096.0f;
#pragma unroll
  for (int h = 0; h < 4; ++h){
    int hq = h0 + hh + h;
    float dd = D[hq*256 + hq] * invN;
#pragma unroll
    for (int j = 0; j < 2; ++j)
      M[(size_t)hq*NF + w0 + lane + 64*j] = make_float2(accr[j][h] + dd, acci[j][h]);
  }
}

// ------------- main: z = u0 + i u1 ; FFT ; *M ; IFFT ; tanh ; store ------------------
// PROVEN round-8/9 configuration byte-for-byte (phys8, 36 KiB, M loads just
// before stage 4). Round-10 lesson: hoisting M loads to entry spills at
// (512,8)'s 64-VGPR budget (+131MB scratch WRITE). Do not hoist.
__global__ __launch_bounds__(512,8) void k_main(
    const float* __restrict__ u, const cf* __restrict__ M, float* __restrict__ out){
  __shared__ cf X[4608];                 // 36 KiB
  const int t  = threadIdx.x;
  const int h  = blockIdx.x >> 3;
  const int pr = blockIdx.x & 7;
  const size_t row0 = ((size_t)pr*256 + h)*(size_t)NF;
  const size_t row1 = row0 + (size_t)8*256*NF;
  const float* u0 = u + row0;
  const float* u1 = u + row1;
  cf v[8];
  // fwd stage 1 (span 4096)
#pragma unroll
  for (int q = 0; q < 8; ++q) v[q] = make_float2(u0[t + 512*q], u1[t + 512*q]);
  dft8<0>(v);
  twiddle8(v, -(PI2F/4096.0f)*(float)t);
#pragma unroll
  for (int r = 0; r < 8; ++r) X[phys8(t + 512*r)] = v[r];
  __syncthreads();
  // fwd stage 2 (span 512)
  const int b2 = ((t >> 6) << 9) | (t & 63);
#pragma unroll
  for (int q = 0; q < 8; ++q) v[q] = X[phys8(b2 + 64*q)];
  dft8<0>(v);
  twiddle8(v, -(PI2F/512.0f)*(float)(t & 63));
#pragma unroll
  for (int r = 0; r < 8; ++r) X[phys8(b2 + 64*r)] = v[r];
  __syncthreads();
  // fwd stage 3 (span 64)
  const int b3 = ((t >> 3) << 6) | (t & 7);
#pragma unroll
  for (int q = 0; q < 8; ++q) v[q] = X[phys8(b3 + 8*q)];
  dft8<0>(v);
  twiddle8(v, -(PI2F/64.0f)*(float)(t & 7));
#pragma unroll
  for (int r = 0; r < 8; ++r) X[phys8(b3 + 8*r)] = v[r];
  __syncthreads();
  // M loads issued before stage-4 LDS reads: global latency hides under LDS+dft8
  float4 mf0, mf1;
  {
    const float4* Mr = (const float4*)(M + (size_t)h*NF + 8*t);
    mf0 = Mr[0]; mf1 = Mr[1];
  }
  // fwd stage 4 (span 8, contiguous) + pointwise + inv stage 1, in registers
#pragma unroll
  for (int q = 0; q < 8; ++q) v[q] = X[phys8(8*t + q)];
  dft8<0>(v);
  {
    const float4* Mr = (const float4*)(M + (size_t)h*NF + 8*t);
    float4 f2 = Mr[2], f3 = Mr[3];
    v[0] = cmulf(v[0], make_float2(mf0.x, mf0.y));
    v[1] = cmulf(v[1], make_float2(mf0.z, mf0.w));
    v[2] = cmulf(v[2], make_float2(mf1.x, mf1.y));
    v[3] = cmulf(v[3], make_float2(mf1.z, mf1.w));
    v[4] = cmulf(v[4], make_float2(f2.x, f2.y));
    v[5] = cmulf(v[5], make_float2(f2.z, f2.w));
    v[6] = cmulf(v[6], make_float2(f3.x, f3.y));
    v[7] = cmulf(v[7], make_float2(f3.z, f3.w));
  }
  dft8<1>(v);
#pragma unroll
  for (int q = 0; q < 8; ++q) X[phys8(8*t + q)] = v[q];
  __syncthreads();
  // inv stage 3
#pragma unroll
  for (int r = 0; r < 8; ++r) v[r] = X[phys8(b3 + 8*r)];
  twiddle8(v, (PI2F/64.0f)*(float)(t & 7));
  dft8<1>(v);
#pragma unroll
  for (int q = 0; q < 8; ++q) X[phys8(b3 + 8*q)] = v[q];
  __syncthreads();
  // inv stage 2
#pragma unroll
  for (int r = 0; r < 8; ++r) v[r] = X[phys8(b2 + 64*r)];
  twiddle8(v, (PI2F/512.0f)*(float)(t & 63));
  dft8<1>(v);
#pragma unroll
  for (int q = 0; q < 8; ++q) X[phys8(b2 + 64*q)] = v[q];
  __syncthreads();
  // inv stage 1 + epilogue
#pragma unroll
  for (int r = 0; r < 8; ++r) v[r] = X[phys8(t + 512*r)];
  twiddle8(v, (PI2F/4096.0f)*(float)t);
  dft8<1>(v);
  float* o0 = out + row0;
  float* o1 = out + row1;
#pragma unroll
  for (int q = 0; q < 8; ++q){
    o0[t + 512*q] = fast_tanh(v[q].x);
    o1[t + 512*q] = fast_tanh(v[q].y);
  }
}

extern "C" void kernel_launch(void* const* d_in, const int* in_sizes, int n_in,
                              void* d_out, int out_size, void* d_ws, size_t ws_size,
                              hipStream_t stream){
  const float* u   = (const float*)d_in[0];
  const float* C   = (const float*)d_in[1];
  const float* D   = (const float*)d_in[2];
  const float* Bb  = (const float*)d_in[3];
  const float* Lam = (const float*)d_in[4];
  float* out = (float*)d_out;
  char* ws = (char*)d_ws;
  cf*     M   = (cf*)ws;                              // 8 MiB: [256][4096] cf, rev8 slot order
  float4* tab = (float4*)(ws + (size_t)(8u << 20));   // 4 MiB: [64][4096] float4 (A, iB)

  k_geo <<<dim3(64),   dim3(1024), 0, stream>>>(Lam, tab);
  k_red <<<dim3(256),  dim3(512),  0, stream>>>(C, Bb, tab, D, M);
  k_main<<<dim3(2048), dim3(512),  0, stream>>>(u, M, out);
}

// Round 12
// 63.628 us; speedup vs baseline: 1.5126x; 1.0237x over previous
//
#include <hip/hip_runtime.h>
#include <cmath>

#define NF 4096
#define PI2F 6.2831853071795864769f

typedef float2 cf;

__device__ __forceinline__ cf cmulf(cf a, cf b){
  return make_float2(fmaf(a.x, b.x, -(a.y*b.y)), fmaf(a.x, b.y, a.y*b.x));
}
__device__ __forceinline__ cf cadd(cf a, cf b){ return make_float2(a.x+b.x, a.y+b.y); }
__device__ __forceinline__ cf csub(cf a, cf b){ return make_float2(a.x-b.x, a.y-b.y); }

// ---- k_main LDS map: additive pad (PROVEN 52us config, rounds 5/6/8/9/11) ----
__device__ __forceinline__ int phys8(int i){ return i + (i >> 3); }

// base-8 digit reversal of a 12-bit index (involution): slot w <-> true freq k
__device__ __forceinline__ int rev8(int i){
  return ((i & 7) << 9) | (((i >> 3) & 7) << 6) | (((i >> 6) & 7) << 3) | ((i >> 9) & 7);
}

// radix-8 DFT in registers; INV=0 forward (e^{-i}), INV=1 inverse (e^{+i}), unnormalized.
template<int INV>
__device__ __forceinline__ void dft8(cf* v){
  const float HF = 0.7071067811865476f;
  cf e0,e1,e2,e3,o0,o1,o2,o3;
  {
    cf t0 = cadd(v[0], v[4]);
    cf t1 = csub(v[0], v[4]);
    cf t2 = cadd(v[2], v[6]);
    cf t3 = csub(v[2], v[6]);
    e0 = cadd(t0,t2); e2 = csub(t0,t2);
    if (!INV){ e1 = make_float2(t1.x+t3.y, t1.y-t3.x); e3 = make_float2(t1.x-t3.y, t1.y+t3.x); }
    else     { e1 = make_float2(t1.x-t3.y, t1.y+t3.x); e3 = make_float2(t1.x+t3.y, t1.y-t3.x); }
  }
  {
    cf t0 = cadd(v[1], v[5]);
    cf t1 = csub(v[1], v[5]);
    cf t2 = cadd(v[3], v[7]);
    cf t3 = csub(v[3], v[7]);
    o0 = cadd(t0,t2); o2 = csub(t0,t2);
    if (!INV){ o1 = make_float2(t1.x+t3.y, t1.y-t3.x); o3 = make_float2(t1.x-t3.y, t1.y+t3.x); }
    else     { o1 = make_float2(t1.x-t3.y, t1.y+t3.x); o3 = make_float2(t1.x+t3.y, t1.y-t3.x); }
  }
  cf w1, w2, w3;
  if (!INV){
    w1 = make_float2(HF*(o1.x + o1.y), HF*(o1.y - o1.x));
    w2 = make_float2(o2.y, -o2.x);
    w3 = make_float2(HF*(o3.y - o3.x), -HF*(o3.x + o3.y));
  } else {
    w1 = make_float2(HF*(o1.x - o1.y), HF*(o1.y + o1.x));
    w2 = make_float2(-o2.y, o2.x);
    w3 = make_float2(-HF*(o3.x + o3.y), HF*(o3.x - o3.y));
  }
  v[0] = cadd(e0,o0); v[4] = csub(e0,o0);
  v[1] = cadd(e1,w1); v[5] = csub(e1,w1);
  v[2] = cadd(e2,w2); v[6] = csub(e2,w2);
  v[3] = cadd(e3,w3); v[7] = csub(e3,w3);
}

// v[r] *= e^{i*ang*r}, r=1..7. Chebyshev power build: T_{r+1} = 2c*T_r - T_{r-1}
__device__ __forceinline__ void twiddle8(cf* v, float ang){
  float s, c;
  __sincosf(ang, &s, &c);
  float c2 = 2.0f * c;
  cf T[8];
  T[1] = make_float2(c, s);
  T[2] = make_float2(fmaf(c2, c, -1.0f), c2 * s);
#pragma unroll
  for (int r = 3; r < 8; ++r)
    T[r] = make_float2(fmaf(c2, T[r-1].x, -T[r-2].x), fmaf(c2, T[r-1].y, -T[r-2].y));
#pragma unroll
  for (int r = 1; r < 8; ++r) v[r] = cmulf(v[r], T[r]);
}

__device__ __forceinline__ float fast_tanh(float x){
  float e = __expf(2.0f*x);
  return 1.0f - __fdividef(2.0f, e + 1.0f);
}

// ---------------- k_mk: fused spectral-table + reduction --------------------------
// M[h][w] = sum_p Wr[h,p]*A[p,w] + Wi[h,p]*B2[p,w]  (+ D[h,h]/N on real part),
// where (A,B2) is the closed-form DFT of the truncated geometric series:
//   G(k) = (1-lam^N)/(1-lam*cis(-2pi k/N));  A=(G1+conj(G2))/2N; B2=i(G1-conj(G2))/2N
// Table entries are COMPUTED on the fly per block (4 transcendental + ~25 VALU each)
// instead of the old global tab round-trip (4 MiB write + 32 MiB read + 1 launch).
// Phase A: lanes 0..63 compute per-p constants in f64 once per block.
// grid: hg(8) x ls(32) = 256 blocks, 512 threads = 8 waves x 4 h each.
__global__ __launch_bounds__(512,4) void k_mk(
    const float* __restrict__ C, const float* __restrict__ Bb,
    const float* __restrict__ Lam, const float* __restrict__ D,
    cf* __restrict__ M){
  __shared__ cf Wsh[32][64];          // 16 KiB
  __shared__ float4 Tt[8][128];       // 16 KiB
  __shared__ float pcs[4][64];        // 1 KiB: tt, r, numr, numi per p
  const int t  = threadIdx.x;
  const int hg = blockIdx.x >> 5;     // 0..7
  const int ls = blockIdx.x & 31;     // 0..31
  const int h0 = hg*32;
  const int w0 = ls*128;
  // stage W = C[h,p]*Bb[p,h]: 2048 entries, 4 per thread
#pragma unroll
  for (int e = 0; e < 4; ++e){
    int idx = e*512 + t;
    int hl = idx >> 6, p = idx & 63;
    int h = h0 + hl;
    cf cc = ((const cf*)C)[h*64 + p];
    cf bb = ((const cf*)Bb)[p*256 + h];
    Wsh[hl][p] = cmulf(cc, bb);
  }
  // per-p constants (f64, once per block; one wave, overlaps with W-load drains)
  if (t < 64){
    int p = t;
    double lr = (double)Lam[2*p], li = (double)Lam[2*p+1];
    double r2 = lr*lr + li*li;
    double tt = atan2(li, lr) * 0.15915494309189535;   // phase in turns
    double rN = exp2(4096.0 * (0.5 * log2(r2)));       // |lambda|^N
    double pN = 4096.0 * tt;  pN -= floor(pN);
    double sN, cN;  sincospi(2.0*pN, &sN, &cN);
    pcs[0][p] = (float)tt;
    pcs[1][p] = (float)sqrt(r2);
    pcs[2][p] = (float)(1.0 - rN*cN);                  // num.re
    pcs[3][p] = (float)(-rN*sN);                       // num.im
  }
  const int wave = t >> 6;
  const int lane = t & 63;
  const int hh = wave*4;              // this wave's 4 local h
  const float hN = 0.5f/4096.0f;
  float accr[2][4] = {{0,0,0,0},{0,0,0,0}};
  float acci[2][4] = {{0,0,0,0},{0,0,0,0}};
  for (int pc = 0; pc < 8; ++pc){
    __syncthreads();                  // Tt free to overwrite; pcs/Wsh ready (iter 0)
    // compute this chunk's 8p x 128w tile: 1024 entries, 2 per thread
#pragma unroll
    for (int e = 0; e < 2; ++e){
      int idx = e*512 + t;
      int row = idx >> 7, col = idx & 127;
      int p = pc*8 + row;
      float tt = pcs[0][p], r = pcs[1][p], numr = pcs[2][p], numi = pcs[3][p];
      int w = w0 + col;
      int k = rev8(w);
      float kf = (float)k * (1.0f/4096.0f);
      float s1, c1;  sincospif(2.0f*(tt - kf), &s1, &c1);
      float d1r = fmaf(-r, c1, 1.0f), d1i = -r*s1;
      float i1 = 1.0f / fmaf(d1r, d1r, d1i*d1i);
      float g1r = (numr*d1r + numi*d1i)*i1;
      float g1i = (numi*d1r - numr*d1i)*i1;
      float s2, c2;  sincospif(2.0f*(tt + kf), &s2, &c2);
      float d2r = fmaf(-r, c2, 1.0f), d2i = -r*s2;
      float i2 = 1.0f / fmaf(d2r, d2r, d2i*d2i);
      float g2r = (numr*d2r + numi*d2i)*i2;
      float g2i = (numi*d2r - numr*d2i)*i2;
      Tt[row][col] = make_float4( (g1r + g2r)*hN, (g1i - g2i)*hN,
                                 -(g1i + g2i)*hN, (g1r - g2r)*hN);
    }
    __syncthreads();
#pragma unroll
    for (int p = 0; p < 8; ++p){
      cf Wc[4];
#pragma unroll
      for (int h = 0; h < 4; ++h) Wc[h] = Wsh[hh + h][pc*8 + p];   // broadcast
#pragma unroll
      for (int j = 0; j < 2; ++j){
        float4 f = Tt[p][lane + 64*j];
#pragma unroll
        for (int h = 0; h < 4; ++h){
          accr[j][h] = fmaf(Wc[h].x, f.x, fmaf(Wc[h].y, f.z, accr[j][h]));
          acci[j][h] = fmaf(Wc[h].x, f.y, fmaf(Wc[h].y, f.w, acci[j][h]));
        }
      }
    }
  }
  const float invN = 1.0f/4096.0f;
#pragma unroll
  for (int h = 0; h < 4; ++h){
    int hq = h0 + hh + h;
    float dd = D[hq*256 + hq] * invN;
#pragma unroll
    for (int j = 0; j < 2; ++j)
      M[(size_t)hq*NF + w0 + lane + 64*j] = make_float2(accr[j][h] + dd, acci[j][h]);
  }
}

// ------------- main: z = u0 + i u1 ; FFT ; *M ; IFFT ; tanh ; store ------------------
// PROVEN round-8/9/11 configuration byte-for-byte (phys8, 36 KiB, M loads just
// before stage 4). Round-10 lesson: hoisting M loads to entry spills at
// (512,8)'s 64-VGPR budget (+131MB scratch WRITE). Do not hoist. LOCKED.
__global__ __launch_bounds__(512,8) void k_main(
    const float* __restrict__ u, const cf* __restrict__ M, float* __restrict__ out){
  __shared__ cf X[4608];                 // 36 KiB
  const int t  = threadIdx.x;
  const int h  = blockIdx.x >> 3;
  const int pr = blockIdx.x & 7;
  const size_t row0 = ((size_t)pr*256 + h)*(size_t)NF;
  const size_t row1 = row0 + (size_t)8*256*NF;
  const float* u0 = u + row0;
  const float* u1 = u + row1;
  cf v[8];
  // fwd stage 1 (span 4096)
#pragma unroll
  for (int q = 0; q < 8; ++q) v[q] = make_float2(u0[t + 512*q], u1[t + 512*q]);
  dft8<0>(v);
  twiddle8(v, -(PI2F/4096.0f)*(float)t);
#pragma unroll
  for (int r = 0; r < 8; ++r) X[phys8(t + 512*r)] = v[r];
  __syncthreads();
  // fwd stage 2 (span 512)
  const int b2 = ((t >> 6) << 9) | (t & 63);
#pragma unroll
  for (int q = 0; q < 8; ++q) v[q] = X[phys8(b2 + 64*q)];
  dft8<0>(v);
  twiddle8(v, -(PI2F/512.0f)*(float)(t & 63));
#pragma unroll
  for (int r = 0; r < 8; ++r) X[phys8(b2 + 64*r)] = v[r];
  __syncthreads();
  // fwd stage 3 (span 64)
  const int b3 = ((t >> 3) << 6) | (t & 7);
#pragma unroll
  for (int q = 0; q < 8; ++q) v[q] = X[phys8(b3 + 8*q)];
  dft8<0>(v);
  twiddle8(v, -(PI2F/64.0f)*(float)(t & 7));
#pragma unroll
  for (int r = 0; r < 8; ++r) X[phys8(b3 + 8*r)] = v[r];
  __syncthreads();
  // M loads issued before stage-4 LDS reads: global latency hides under LDS+dft8
  float4 mf0, mf1;
  {
    const float4* Mr = (const float4*)(M + (size_t)h*NF + 8*t);
    mf0 = Mr[0]; mf1 = Mr[1];
  }
  // fwd stage 4 (span 8, contiguous) + pointwise + inv stage 1, in registers
#pragma unroll
  for (int q = 0; q < 8; ++q) v[q] = X[phys8(8*t + q)];
  dft8<0>(v);
  {
    const float4* Mr = (const float4*)(M + (size_t)h*NF + 8*t);
    float4 f2 = Mr[2], f3 = Mr[3];
    v[0] = cmulf(v[0], make_float2(mf0.x, mf0.y));
    v[1] = cmulf(v[1], make_float2(mf0.z, mf0.w));
    v[2] = cmulf(v[2], make_float2(mf1.x, mf1.y));
    v[3] = cmulf(v[3], make_float2(mf1.z, mf1.w));
    v[4] = cmulf(v[4], make_float2(f2.x, f2.y));
    v[5] = cmulf(v[5], make_float2(f2.z, f2.w));
    v[6] = cmulf(v[6], make_float2(f3.x, f3.y));
    v[7] = cmulf(v[7], make_float2(f3.z, f3.w));
  }
  dft8<1>(v);
#pragma unroll
  for (int q = 0; q < 8; ++q) X[phys8(8*t + q)] = v[q];
  __syncthreads();
  // inv stage 3
#pragma unroll
  for (int r = 0; r < 8; ++r) v[r] = X[phys8(b3 + 8*r)];
  twiddle8(v, (PI2F/64.0f)*(float)(t & 7));
  dft8<1>(v);
#pragma unroll
  for (int q = 0; q < 8; ++q) X[phys8(b3 + 8*q)] = v[q];
  __syncthreads();
  // inv stage 2
#pragma unroll
  for (int r = 0; r < 8; ++r) v[r] = X[phys8(b2 + 64*r)];
  twiddle8(v, (PI2F/512.0f)*(float)(t & 63));
  dft8<1>(v);
#pragma unroll
  for (int q = 0; q < 8; ++q) X[phys8(b2 + 64*q)] = v[q];
  __syncthreads();
  // inv stage 1 + epilogue
#pragma unroll
  for (int r = 0; r < 8; ++r) v[r] = X[phys8(t + 512*r)];
  twiddle8(v, (PI2F/4096.0f)*(float)t);
  dft8<1>(v);
  float* o0 = out + row0;
  float* o1 = out + row1;
#pragma unroll
  for (int q = 0; q < 8; ++q){
    o0[t + 512*q] = fast_tanh(v[q].x);
    o1[t + 512*q] = fast_tanh(v[q].y);
  }
}

extern "C" void kernel_launch(void* const* d_in, const int* in_sizes, int n_in,
                              void* d_out, int out_size, void* d_ws, size_t ws_size,
                              hipStream_t stream){
  const float* u   = (const float*)d_in[0];
  const float* C   = (const float*)d_in[1];
  const float* D   = (const float*)d_in[2];
  const float* Bb  = (const float*)d_in[3];
  const float* Lam = (const float*)d_in[4];
  float* out = (float*)d_out;
  char* ws = (char*)d_ws;
  cf* M = (cf*)ws;                    // 8 MiB: [256][4096] cf, rev8 slot order

  k_mk  <<<dim3(256),  dim3(512), 0, stream>>>(C, Bb, Lam, D, M);
  k_main<<<dim3(2048), dim3(512), 0, stream>>>(u, M, out);
}

// Round 13
// 62.956 us; speedup vs baseline: 1.5287x; 1.0107x over previous
//
#include <hip/hip_runtime.h>
#include <cmath>

#define NF 4096
#define PI2F 6.2831853071795864769f

typedef float2 cf;

__device__ __forceinline__ cf cmulf(cf a, cf b){
  return make_float2(fmaf(a.x, b.x, -(a.y*b.y)), fmaf(a.x, b.y, a.y*b.x));
}
__device__ __forceinline__ cf cadd(cf a, cf b){ return make_float2(a.x+b.x, a.y+b.y); }
__device__ __forceinline__ cf csub(cf a, cf b){ return make_float2(a.x-b.x, a.y-b.y); }

// ---- k_main LDS map: additive pad (PROVEN config). Monotone -> maps each
// wave's 512-cf span to a disjoint 576-cf span: wave-privacy preserved. ----
__device__ __forceinline__ int phys8(int i){ return i + (i >> 3); }

// base-8 digit reversal of a 12-bit index (involution): slot w <-> true freq k
__device__ __forceinline__ int rev8(int i){
  return ((i & 7) << 9) | (((i >> 3) & 7) << 6) | (((i >> 6) & 7) << 3) | ((i >> 9) & 7);
}

// radix-8 DFT in registers; INV=0 forward (e^{-i}), INV=1 inverse (e^{+i}), unnormalized.
template<int INV>
__device__ __forceinline__ void dft8(cf* v){
  const float HF = 0.7071067811865476f;
  cf e0,e1,e2,e3,o0,o1,o2,o3;
  {
    cf t0 = cadd(v[0], v[4]);
    cf t1 = csub(v[0], v[4]);
    cf t2 = cadd(v[2], v[6]);
    cf t3 = csub(v[2], v[6]);
    e0 = cadd(t0,t2); e2 = csub(t0,t2);
    if (!INV){ e1 = make_float2(t1.x+t3.y, t1.y-t3.x); e3 = make_float2(t1.x-t3.y, t1.y+t3.x); }
    else     { e1 = make_float2(t1.x-t3.y, t1.y+t3.x); e3 = make_float2(t1.x+t3.y, t1.y-t3.x); }
  }
  {
    cf t0 = cadd(v[1], v[5]);
    cf t1 = csub(v[1], v[5]);
    cf t2 = cadd(v[3], v[7]);
    cf t3 = csub(v[3], v[7]);
    o0 = cadd(t0,t2); o2 = csub(t0,t2);
    if (!INV){ o1 = make_float2(t1.x+t3.y, t1.y-t3.x); o3 = make_float2(t1.x-t3.y, t1.y+t3.x); }
    else     { o1 = make_float2(t1.x-t3.y, t1.y+t3.x); o3 = make_float2(t1.x+t3.y, t1.y-t3.x); }
  }
  cf w1, w2, w3;
  if (!INV){
    w1 = make_float2(HF*(o1.x + o1.y), HF*(o1.y - o1.x));
    w2 = make_float2(o2.y, -o2.x);
    w3 = make_float2(HF*(o3.y - o3.x), -HF*(o3.x + o3.y));
  } else {
    w1 = make_float2(HF*(o1.x - o1.y), HF*(o1.y + o1.x));
    w2 = make_float2(-o2.y, o2.x);
    w3 = make_float2(-HF*(o3.x + o3.y), HF*(o3.x - o3.y));
  }
  v[0] = cadd(e0,o0); v[4] = csub(e0,o0);
  v[1] = cadd(e1,w1); v[5] = csub(e1,w1);
  v[2] = cadd(e2,w2); v[6] = csub(e2,w2);
  v[3] = cadd(e3,w3); v[7] = csub(e3,w3);
}

// v[r] *= e^{i*ang*r}, r=1..7. Chebyshev power build: T_{r+1} = 2c*T_r - T_{r-1}
__device__ __forceinline__ void twiddle8(cf* v, float ang){
  float s, c;
  __sincosf(ang, &s, &c);
  float c2 = 2.0f * c;
  cf T[8];
  T[1] = make_float2(c, s);
  T[2] = make_float2(fmaf(c2, c, -1.0f), c2 * s);
#pragma unroll
  for (int r = 3; r < 8; ++r)
    T[r] = make_float2(fmaf(c2, T[r-1].x, -T[r-2].x), fmaf(c2, T[r-1].y, -T[r-2].y));
#pragma unroll
  for (int r = 1; r < 8; ++r) v[r] = cmulf(v[r], T[r]);
}

__device__ __forceinline__ float fast_tanh(float x){
  float e = __expf(2.0f*x);
  return 1.0f - __fdividef(2.0f, e + 1.0f);
}

// compiler-only fence: pins LDS phase ordering without any runtime cost
#define PHASE_FENCE() asm volatile("" ::: "memory")

// ---------------- k_mk: fused spectral-table + reduction (round-12 proven) --------
__global__ __launch_bounds__(512,4) void k_mk(
    const float* __restrict__ C, const float* __restrict__ Bb,
    const float* __restrict__ Lam, const float* __restrict__ D,
    cf* __restrict__ M){
  __shared__ cf Wsh[32][64];          // 16 KiB
  __shared__ float4 Tt[8][128];       // 16 KiB
  __shared__ float pcs[4][64];        // 1 KiB: tt, r, numr, numi per p
  const int t  = threadIdx.x;
  const int hg = blockIdx.x >> 5;     // 0..7
  const int ls = blockIdx.x & 31;     // 0..31
  const int h0 = hg*32;
  const int w0 = ls*128;
#pragma unroll
  for (int e = 0; e < 4; ++e){
    int idx = e*512 + t;
    int hl = idx >> 6, p = idx & 63;
    int h = h0 + hl;
    cf cc = ((const cf*)C)[h*64 + p];
    cf bb = ((const cf*)Bb)[p*256 + h];
    Wsh[hl][p] = cmulf(cc, bb);
  }
  if (t < 64){
    int p = t;
    double lr = (double)Lam[2*p], li = (double)Lam[2*p+1];
    double r2 = lr*lr + li*li;
    double tt = atan2(li, lr) * 0.15915494309189535;   // phase in turns
    double rN = exp2(4096.0 * (0.5 * log2(r2)));       // |lambda|^N
    double pN = 4096.0 * tt;  pN -= floor(pN);
    double sN, cN;  sincospi(2.0*pN, &sN, &cN);
    pcs[0][p] = (float)tt;
    pcs[1][p] = (float)sqrt(r2);
    pcs[2][p] = (float)(1.0 - rN*cN);                  // num.re
    pcs[3][p] = (float)(-rN*sN);                       // num.im
  }
  const int wave = t >> 6;
  const int lane = t & 63;
  const int hh = wave*4;              // this wave's 4 local h
  const float hN = 0.5f/4096.0f;
  float accr[2][4] = {{0,0,0,0},{0,0,0,0}};
  float acci[2][4] = {{0,0,0,0},{0,0,0,0}};
  for (int pc = 0; pc < 8; ++pc){
    __syncthreads();
#pragma unroll
    for (int e = 0; e < 2; ++e){
      int idx = e*512 + t;
      int row = idx >> 7, col = idx & 127;
      int p = pc*8 + row;
      float tt = pcs[0][p], r = pcs[1][p], numr = pcs[2][p], numi = pcs[3][p];
      int w = w0 + col;
      int k = rev8(w);
      float kf = (float)k * (1.0f/4096.0f);
      float s1, c1;  sincospif(2.0f*(tt - kf), &s1, &c1);
      float d1r = fmaf(-r, c1, 1.0f), d1i = -r*s1;
      float i1 = 1.0f / fmaf(d1r, d1r, d1i*d1i);
      float g1r = (numr*d1r + numi*d1i)*i1;
      float g1i = (numi*d1r - numr*d1i)*i1;
      float s2, c2;  sincospif(2.0f*(tt + kf), &s2, &c2);
      float d2r = fmaf(-r, c2, 1.0f), d2i = -r*s2;
      float i2 = 1.0f / fmaf(d2r, d2r, d2i*d2i);
      float g2r = (numr*d2r + numi*d2i)*i2;
      float g2i = (numi*d2r - numr*d2i)*i2;
      Tt[row][col] = make_float4( (g1r + g2r)*hN, (g1i - g2i)*hN,
                                 -(g1i + g2i)*hN, (g1r - g2r)*hN);
    }
    __syncthreads();
#pragma unroll
    for (int p = 0; p < 8; ++p){
      cf Wc[4];
#pragma unroll
      for (int h = 0; h < 4; ++h) Wc[h] = Wsh[hh + h][pc*8 + p];   // broadcast
#pragma unroll
      for (int j = 0; j < 2; ++j){
        float4 f = Tt[p][lane + 64*j];
#pragma unroll
        for (int h = 0; h < 4; ++h){
          accr[j][h] = fmaf(Wc[h].x, f.x, fmaf(Wc[h].y, f.z, accr[j][h]));
          acci[j][h] = fmaf(Wc[h].x, f.y, fmaf(Wc[h].y, f.w, acci[j][h]));
        }
      }
    }
  }
  const float invN = 1.0f/4096.0f;
#pragma unroll
  for (int h = 0; h < 4; ++h){
    int hq = h0 + hh + h;
    float dd = D[hq*256 + hq] * invN;
#pragma unroll
    for (int j = 0; j < 2; ++j)
      M[(size_t)hq*NF + w0 + lane + 64*j] = make_float2(accr[j][h] + dd, acci[j][h]);
  }
}

// ------------- main: z = u0 + i u1 ; FFT ; *M ; IFFT ; tanh ; store ------------------
// Round-12 change: BARRIER ELIMINATION. After fwd stage 1's cross-wave scatter,
// stages 2,3,4, pointwise, inv-1', inv-3, inv-2 all touch ONLY this wave's
// 512-cf span ([512w,512w+512) -> phys8-mapped [576w,576w+576), disjoint).
// Within-wave RAW through LDS is hazard-free (in-order LDS pipe + compiler
// lgkmcnt waits). Only 2 __syncthreads remain: after fwd-1 write, before
// inv-1 read. Everything else byte-identical to the proven 52us config.
__global__ __launch_bounds__(512,8) void k_main(
    const float* __restrict__ u, const cf* __restrict__ M, float* __restrict__ out){
  __shared__ cf X[4608];                 // 36 KiB
  const int t  = threadIdx.x;
  const int h  = blockIdx.x >> 3;
  const int pr = blockIdx.x & 7;
  const size_t row0 = ((size_t)pr*256 + h)*(size_t)NF;
  const size_t row1 = row0 + (size_t)8*256*NF;
  const float* u0 = u + row0;
  const float* u1 = u + row1;
  cf v[8];
  // fwd stage 1 (span 4096) — cross-wave scatter
#pragma unroll
  for (int q = 0; q < 8; ++q) v[q] = make_float2(u0[t + 512*q], u1[t + 512*q]);
  dft8<0>(v);
  twiddle8(v, -(PI2F/4096.0f)*(float)t);
#pragma unroll
  for (int r = 0; r < 8; ++r) X[phys8(t + 512*r)] = v[r];
  __syncthreads();                       // BARRIER 1 of 2
  // fwd stage 2 (span 512) — wave-private
  const int b2 = ((t >> 6) << 9) | (t & 63);
#pragma unroll
  for (int q = 0; q < 8; ++q) v[q] = X[phys8(b2 + 64*q)];
  dft8<0>(v);
  twiddle8(v, -(PI2F/512.0f)*(float)(t & 63));
#pragma unroll
  for (int r = 0; r < 8; ++r) X[phys8(b2 + 64*r)] = v[r];
  PHASE_FENCE();
  // fwd stage 3 (span 64) — wave-private
  const int b3 = ((t >> 3) << 6) | (t & 7);
#pragma unroll
  for (int q = 0; q < 8; ++q) v[q] = X[phys8(b3 + 8*q)];
  dft8<0>(v);
  twiddle8(v, -(PI2F/64.0f)*(float)(t & 7));
#pragma unroll
  for (int r = 0; r < 8; ++r) X[phys8(b3 + 8*r)] = v[r];
  PHASE_FENCE();
  // M loads just before stage 4 (PROVEN placement; hoist spills — round 10)
  float4 mf0, mf1;
  {
    const float4* Mr = (const float4*)(M + (size_t)h*NF + 8*t);
    mf0 = Mr[0]; mf1 = Mr[1];
  }
  // fwd stage 4 (span 8) + pointwise + inv stage 1', in registers — wave-private
#pragma unroll
  for (int q = 0; q < 8; ++q) v[q] = X[phys8(8*t + q)];
  dft8<0>(v);
  {
    const float4* Mr = (const float4*)(M + (size_t)h*NF + 8*t);
    float4 f2 = Mr[2], f3 = Mr[3];
    v[0] = cmulf(v[0], make_float2(mf0.x, mf0.y));
    v[1] = cmulf(v[1], make_float2(mf0.z, mf0.w));
    v[2] = cmulf(v[2], make_float2(mf1.x, mf1.y));
    v[3] = cmulf(v[3], make_float2(mf1.z, mf1.w));
    v[4] = cmulf(v[4], make_float2(f2.x, f2.y));
    v[5] = cmulf(v[5], make_float2(f2.z, f2.w));
    v[6] = cmulf(v[6], make_float2(f3.x, f3.y));
    v[7] = cmulf(v[7], make_float2(f3.z, f3.w));
  }
  dft8<1>(v);
#pragma unroll
  for (int q = 0; q < 8; ++q) X[phys8(8*t + q)] = v[q];
  PHASE_FENCE();
  // inv stage 3 — wave-private
#pragma unroll
  for (int r = 0; r < 8; ++r) v[r] = X[phys8(b3 + 8*r)];
  twiddle8(v, (PI2F/64.0f)*(float)(t & 7));
  dft8<1>(v);
#pragma unroll
  for (int q = 0; q < 8; ++q) X[phys8(b3 + 8*q)] = v[q];
  PHASE_FENCE();
  // inv stage 2 — wave-private writes, then cross-wave reads follow
#pragma unroll
  for (int r = 0; r < 8; ++r) v[r] = X[phys8(b2 + 64*r)];
  twiddle8(v, (PI2F/512.0f)*(float)(t & 63));
  dft8<1>(v);
#pragma unroll
  for (int q = 0; q < 8; ++q) X[phys8(b2 + 64*q)] = v[q];
  __syncthreads();                       // BARRIER 2 of 2
  // inv stage 1 (span 4096) + epilogue — cross-wave gather
#pragma unroll
  for (int r = 0; r < 8; ++r) v[r] = X[phys8(t + 512*r)];
  twiddle8(v, (PI2F/4096.0f)*(float)t);
  dft8<1>(v);
  float* o0 = out + row0;
  float* o1 = out + row1;
#pragma unroll
  for (int q = 0; q < 8; ++q){
    o0[t + 512*q] = fast_tanh(v[q].x);
    o1[t + 512*q] = fast_tanh(v[q].y);
  }
}

extern "C" void kernel_launch(void* const* d_in, const int* in_sizes, int n_in,
                              void* d_out, int out_size, void* d_ws, size_t ws_size,
                              hipStream_t stream){
  const float* u   = (const float*)d_in[0];
  const float* C   = (const float*)d_in[1];
  const float* D   = (const float*)d_in[2];
  const float* Bb  = (const float*)d_in[3];
  const float* Lam = (const float*)d_in[4];
  float* out = (float*)d_out;
  char* ws = (char*)d_ws;
  cf* M = (cf*)ws;                    // 8 MiB: [256][4096] cf, rev8 slot order

  k_mk  <<<dim3(256),  dim3(512), 0, stream>>>(C, Bb, Lam, D, M);
  k_main<<<dim3(2048), dim3(512), 0, stream>>>(u, M, out);
}